// Round 9
// baseline (405.516 us; speedup 1.0000x reference)
//
#include <hip/hip_runtime.h>
#include <stdint.h>

#define HIDDEN 1024
#define HEADS 16
#define HEAD_DIM 64
#define BATCH 4
#define SEQ 2048
#define NTOK (BATCH * SEQ)   // 8192

typedef __attribute__((ext_vector_type(8))) short bf16x8;
typedef __attribute__((ext_vector_type(4))) float floatx4;
typedef __attribute__((ext_vector_type(16))) float floatx16;

// log2(e) / sqrt(HEAD_DIM) : folded into Q so p = exp2(s) directly
#define SCALE_Q 0.18033688011112042f

__device__ __forceinline__ unsigned short f2bf(float f) {
    union { float f; unsigned u; } x; x.f = f;
    unsigned r = x.u + 0x7fffu + ((x.u >> 16) & 1u);
    return (unsigned short)(r >> 16);
}

__device__ __forceinline__ float fast_exp2(float x) {
#if __has_builtin(__builtin_amdgcn_exp2f)
    return __builtin_amdgcn_exp2f(x);
#else
    return exp2f(x);
#endif
}

typedef __attribute__((address_space(3))) unsigned int lds_u32;
typedef const __attribute__((address_space(1))) unsigned int gl_u32;

// async global->LDS, 16B per lane; l is the WAVE-UNIFORM base (HW scatters
// lane i's 16B to l + i*16).
__device__ __forceinline__ void async_cp16(const void* g, void* l) {
#if __has_builtin(__builtin_amdgcn_global_load_lds)
    __builtin_amdgcn_global_load_lds((gl_u32*)g, (lds_u32*)l, 16, 0, 0);
#else
    *(uint4*)((char*)l + (threadIdx.x & 63) * 16) = *(const uint4*)g;
#endif
}

// ---- fused fp32->bf16 conversion for x, Wq, Wk, Wv + zero of accp ----------
__global__ __launch_bounds__(256) void conv_all(
    const float* __restrict__ x, const float* __restrict__ Wq,
    const float* __restrict__ Wk, const float* __restrict__ Wv,
    unsigned short* __restrict__ x_bf, unsigned short* __restrict__ wq_bf,
    unsigned short* __restrict__ wk_bf, unsigned short* __restrict__ wv_bf,
    float* __restrict__ accp) {
    const int blk = blockIdx.x, tid = threadIdx.x;
    const float* src;
    unsigned short* dst;
    size_t i;
    if (blk < 8192) {
        src = x; dst = x_bf; i = (size_t)blk * 256 + tid;
        if (blk < 16) accp[blk * 256 + tid] = 0.0f;
    } else {
        int r = blk - 8192;
        int s = r >> 10;
        src = (s == 0) ? Wq : (s == 1) ? Wk : Wv;
        dst = (s == 0) ? wq_bf : (s == 1) ? wk_bf : wv_bf;
        i = (size_t)(r & 1023) * 256 + tid;
    }
    float4 v = *(const float4*)(src + 4 * i);
    unsigned short o[4];
    o[0] = f2bf(v.x); o[1] = f2bf(v.y); o[2] = f2bf(v.z); o[3] = f2bf(v.w);
    *(ushort4*)(dst + 4 * i) = *(ushort4*)o;
}

// ---- QKV GEMM, single N=3072 GEMM of 128x128 tiles (unchanged from R8) -----
__global__ __launch_bounds__(256, 3) void qkv_gemm(
    const unsigned short* __restrict__ X,
    const unsigned short* __restrict__ W0, const unsigned short* __restrict__ W1,
    const unsigned short* __restrict__ W2,
    const float* __restrict__ b0, const float* __restrict__ b1,
    const float* __restrict__ b2,
    unsigned short* __restrict__ O0, unsigned short* __restrict__ O1,
    unsigned short* __restrict__ O2) {
    __shared__ __align__(16) char smem[34816];   // A dbuf 16K | B dbuf 16K; tbuf aliases
    unsigned short* tbuf = (unsigned short*)smem;

    const int id = blockIdx.x;
    const int mb = id & 63, nzb = id >> 6;
    const int z = nzb >> 3, nz = nzb & 7;
    const int m0 = mb * 128;
    const unsigned short* W = (z == 0) ? W0 : (z == 1) ? W1 : W2;
    const float* bias       = (z == 0) ? b0 : (z == 1) ? b1 : b2;

    const int tid = threadIdx.x, lane = tid & 63, wave = tid >> 6;
    const int wm = (wave & 1) * 64, wn = (wave >> 1) * 64;

    const int srow = lane >> 2;
    const int sxc = ((lane & 3) ^ (srow & 3)) * 8;   // shorts
    const unsigned short* ga[2];
    const unsigned short* gb[2];
#pragma unroll
    for (int j = 0; j < 2; ++j) {
        ga[j] = X + (size_t)(m0 + wave * 32 + j * 16 + srow) * HIDDEN + sxc;
        gb[j] = W + (size_t)(nz * 128 + wave * 32 + j * 16 + srow) * HIDDEN + sxc;
    }

    floatx4 acc[4][4];
#pragma unroll
    for (int tm = 0; tm < 4; ++tm)
#pragma unroll
        for (int tn = 0; tn < 4; ++tn)
#pragma unroll
            for (int r = 0; r < 4; ++r) acc[tm][tn][r] = 0.f;

#pragma unroll
    for (int j = 0; j < 2; ++j) {
        async_cp16(ga[j], smem + wave * 2048 + j * 1024);
        async_cp16(gb[j], smem + 16384 + wave * 2048 + j * 1024);
        ga[j] += 32; gb[j] += 32;
    }
    __syncthreads();

    const int fr = (lane & 15) * 64 + (((lane >> 4) ^ (lane & 3)) * 16);
    for (int kt = 0; kt < 32; ++kt) {
        const int cur = kt & 1;
        if (kt < 31) {
#pragma unroll
            for (int j = 0; j < 2; ++j) {
                async_cp16(ga[j], smem + (cur ^ 1) * 8192 + wave * 2048 + j * 1024);
                async_cp16(gb[j], smem + 16384 + (cur ^ 1) * 8192 + wave * 2048 + j * 1024);
                ga[j] += 32; gb[j] += 32;
            }
        }
        const char* Ab = smem + cur * 8192;
        const char* Bb = smem + 16384 + cur * 8192;
        bf16x8 af[4], bfr[4];
#pragma unroll
        for (int t = 0; t < 4; ++t) {
            af[t]  = *(bf16x8*)(Ab + (wm + t * 16) * 64 + fr);
            bfr[t] = *(bf16x8*)(Bb + (wn + t * 16) * 64 + fr);
        }
#pragma unroll
        for (int tm = 0; tm < 4; ++tm)
#pragma unroll
            for (int tn = 0; tn < 4; ++tn)
                acc[tm][tn] = __builtin_amdgcn_mfma_f32_16x16x32_bf16(af[tm], bfr[tn], acc[tm][tn], 0, 0, 0);
        if (kt < 31) __syncthreads();
    }

    // epilogue via LDS transpose; C/D map: col = lane&15, row = (lane>>4)*4+reg
    const int col = lane & 15, rbase = (lane >> 4) * 4;
    __syncthreads();
    if (z == 2) {
        // V: tbuf [d 0..127][tok 0..127], stride 136; granule perm (swap tok
        // bits 2,3) -> attention PV B-frag = one contiguous 16 B chunk.
#pragma unroll
        for (int tm = 0; tm < 4; ++tm)
#pragma unroll
            for (int tn = 0; tn < 4; ++tn) {
                const int dr = wn + tn * 16 + col;
                const float bs = bias[nz * 128 + dr];
                const int mi0 = wm + tm * 16 + rbase;
                const int mip = (mi0 & ~12) | ((mi0 & 4) << 1) | ((mi0 & 8) >> 1);
                unsigned short vals[4];
#pragma unroll
                for (int r = 0; r < 4; ++r) vals[r] = f2bf(acc[tm][tn][r] + bs);
                *(ushort4*)&tbuf[dr * 136 + mip] = *(ushort4*)vals;
            }
        __syncthreads();
        const int dr = tid >> 1, seg = tid & 1;
        const int hh = nz * 2 + (dr >> 6), dd = dr & 63;
        const int bb = m0 >> 11, tb = (m0 & (SEQ - 1)) >> 7;
        unsigned short* dst = O2 + (((size_t)bb * HEADS + hh) * HEAD_DIM + dd) * SEQ
                                 + tb * 128 + seg * 64;
        const unsigned short* srcl = &tbuf[dr * 136 + seg * 64];
#pragma unroll
        for (int i = 0; i < 8; ++i)
            *(uint4*)(dst + i * 8) = *(const uint4*)(srcl + i * 8);
    } else {
        unsigned short* O = (z == 0) ? O0 : O1;
        const float sc = (z == 0) ? SCALE_Q : 1.0f;
#pragma unroll
        for (int tm = 0; tm < 4; ++tm)
#pragma unroll
            for (int tn = 0; tn < 4; ++tn) {
                const int nn = wn + tn * 16 + col;
                const float bs = bias[nz * 128 + nn];
                const int mi0 = wm + tm * 16 + rbase;
#pragma unroll
                for (int r = 0; r < 4; ++r)
                    tbuf[(mi0 + r) * 136 + nn] = f2bf((acc[tm][tn][r] + bs) * sc);
            }
        __syncthreads();
        const int r = tid >> 1, seg = tid & 1;
        unsigned short* dst = O + (size_t)(m0 + r) * HIDDEN + nz * 128 + seg * 64;
        const unsigned short* srcl = &tbuf[r * 136 + seg * 64];
#pragma unroll
        for (int i = 0; i < 8; ++i)
            *(uint4*)(dst + i * 8) = *(const uint4*)(srcl + i * 8);
    }
}

// ---- MFMA flash attention, NO LDS: fragments direct from global (L1/L2) ----
// grid 1024, 128 q/block, 1 q-group of 32 per wave. No barriers, no staging:
// kf/vf are contiguous 16 B global loads (V granule-perm baked into Vt).
// l accumulated on VALU from the SAME truncated bf16 p values (unpack pk via
// <<16 / &0xFFFF0000) -> bit-compatible with the old ones-MFMA; transposed to
// C-row layout through a 512 B per-wave LDS buffer at the epilogue.
__global__ __launch_bounds__(256, 4) void attn_mfma(
    const unsigned short* __restrict__ Q, const unsigned short* __restrict__ K,
    const unsigned short* __restrict__ Vt, float* __restrict__ accp) {
    __shared__ float lbuf[4][32];

    const int tid = threadIdx.x, lane = tid & 63, wave = tid >> 6;
    const int lq = lane & 31, g2 = lane >> 5;

    const int f = blockIdx.x;
    const int bh = (f & 7) * 8 + ((f >> 3) & 7);
    const int qc = f >> 6;                    // 0..15 (128-q chunk)
    const int b = bh >> 4, h = bh & 15;

    // Q B-fragments (kept in regs whole kernel)
    bf16x8 qfrag[4];
    {
        const size_t qb = ((size_t)(b * SEQ + qc * 128 + wave * 32 + lq)) * HIDDEN
                          + h * HEAD_DIM + g2 * 8;
#pragma unroll
        for (int ds = 0; ds < 4; ++ds) qfrag[ds] = *(const bf16x8*)&Q[qb + ds * 16];
    }

    // K: lane reads key row (32*step + lq), 4 chunks at d = g2*8 + ds*16
    const unsigned short* kp = K + ((size_t)(b * SEQ + lq)) * HIDDEN + h * HEAD_DIM + g2 * 8;
    // V: lane reads d-row (nf*32 + lq), chunk (2s+g2) of the 64-key window
    const unsigned short* vp0 = Vt + ((size_t)(bh * HEAD_DIM) + lq) * SEQ + g2 * 8;
    const unsigned short* vp1 = vp0 + (size_t)32 * SEQ;

    floatx16 oacc[2];
#pragma unroll
    for (int r = 0; r < 16; ++r) { oacc[0][r] = 0.f; oacc[1][r] = 0.f; }
    float lsum = 0.f;

    for (int it = 0; it < 32; ++it) {
        const unsigned short* kwin = kp + (size_t)it * 64 * HIDDEN;
        const unsigned short* vw0 = vp0 + it * 64;
        const unsigned short* vw1 = vp1 + it * 64;
#pragma unroll
        for (int s32 = 0; s32 < 2; ++s32) {
            // issue all 8 loads first (vf latency hides behind S-MFMA+exp)
            bf16x8 kf[4], vf[2][2];
            const unsigned short* kr = kwin + (size_t)s32 * 32 * HIDDEN;
#pragma unroll
            for (int ds = 0; ds < 4; ++ds)
                kf[ds] = *(const bf16x8*)(kr + ds * 16);
#pragma unroll
            for (int ks2 = 0; ks2 < 2; ++ks2) {
                const int ch = (s32 * 2 + ks2) * 16;   // (2s+g2)*8 shorts, g2 in base
                vf[ks2][0] = *(const bf16x8*)(vw0 + ch);
                vf[ks2][1] = *(const bf16x8*)(vw1 + ch);
            }

            // S^T = K·Q^T for 32 keys
            floatx16 sacc;
#pragma unroll
            for (int r = 0; r < 16; ++r) sacc[r] = 0.f;
#pragma unroll
            for (int ds = 0; ds < 4; ++ds)
                sacc = __builtin_amdgcn_mfma_f32_32x32x16_bf16(kf[ds], qfrag[ds], sacc, 0, 0, 0);

            // p = exp2(s), pack to bf16 (truncation), accumulate l from the
            // SAME truncated values
            unsigned pk[8];
#pragma unroll
            for (int j = 0; j < 8; ++j) {
                union { float f; unsigned u; } plo, phi;
                plo.f = fast_exp2(sacc[2 * j]);
                phi.f = fast_exp2(sacc[2 * j + 1]);
                pk[j] = __builtin_amdgcn_perm(phi.u, plo.u, 0x07060302u);
                union { unsigned u; float f; } tlo, thi;
                tlo.u = pk[j] << 16;
                thi.u = pk[j] & 0xFFFF0000u;
                lsum += tlo.f + thi.f;
            }

            // PV: lane's native keys {0-3,8-11}+4g2 per 16-key step; vf is the
            // matching granule-pair chunk (perm baked into Vt)
#pragma unroll
            for (int ks2 = 0; ks2 < 2; ++ks2) {
                union { uint4 u; bf16x8 v; } af;
                af.u.x = pk[4 * ks2];
                af.u.y = pk[4 * ks2 + 1];
                af.u.z = pk[4 * ks2 + 2];
                af.u.w = pk[4 * ks2 + 3];
#pragma unroll
                for (int nf = 0; nf < 2; ++nf)
                    oacc[nf] = __builtin_amdgcn_mfma_f32_32x32x16_bf16(af.v, vf[ks2][nf], oacc[nf], 0, 0, 0);
            }
        }
    }

    // ---- epilogue ----------------------------------------------------------
    // full l per query lq: add the other g2-half, stash per-wave, reload in
    // C-row layout (rows (reg&3)+8*(reg>>2)+4*g2 -> 4 aligned float4 chunks)
    lsum += __shfl_xor(lsum, 32, 64);
    if (lane < 32) lbuf[wave][lq] = lsum;
    __builtin_amdgcn_s_waitcnt(0);   // lgkmcnt(0): same-wave LDS visibility
    float4 l4[4];
#pragma unroll
    for (int c = 0; c < 4; ++c)
        l4[c] = *(float4*)&lbuf[wave][c * 8 + g2 * 4];
    float inv[16];
#pragma unroll
    for (int c = 0; c < 4; ++c) {
        inv[4 * c + 0] = 1.0f / l4[c].x;
        inv[4 * c + 1] = 1.0f / l4[c].y;
        inv[4 * c + 2] = 1.0f / l4[c].z;
        inv[4 * c + 3] = 1.0f / l4[c].w;
    }
#pragma unroll
    for (int nf = 0; nf < 2; ++nf) {
        float v = 0.f;
#pragma unroll
        for (int r = 0; r < 16; ++r) v += oacc[nf][r] * inv[r];
        v += __shfl_xor(v, 32, 64);
        if (lane < 32)
            atomicAdd(&accp[b * HIDDEN + h * HEAD_DIM + nf * 32 + lq], v);
    }
}

// ---- final projection: out = (acc/T) @ Wo^T + bo, split-k x4 ---------------
__global__ __launch_bounds__(256) void out_proj(const float* __restrict__ acc,
                                                const float* __restrict__ Wo,
                                                const float* __restrict__ bo,
                                                float* __restrict__ out) {
    __shared__ float red[256];
    const int n = blockIdx.x * 64 + (threadIdx.x & 63);
    const int ks = threadIdx.x >> 6;       // 0..3
    const int b = blockIdx.y;
    const float* wr = Wo + (size_t)n * HIDDEN + ks * 256;
    const float* ar = acc + b * HIDDEN + ks * 256;
    float s = 0.f;
#pragma unroll 8
    for (int k = 0; k < 256; k += 4) {
        float4 w = *(const float4*)(wr + k);
        float4 a = *(const float4*)(ar + k);
        s += w.x * a.x + w.y * a.y + w.z * a.z + w.w * a.w;
    }
    red[threadIdx.x] = s;
    __syncthreads();
    if (threadIdx.x < 64) {
        float t = red[threadIdx.x] + red[threadIdx.x + 64]
                + red[threadIdx.x + 128] + red[threadIdx.x + 192];
        out[b * HIDDEN + n] = t * (1.0f / (float)SEQ) + bo[n];
    }
}

extern "C" void kernel_launch(void* const* d_in, const int* in_sizes, int n_in,
                              void* d_out, int out_size, void* d_ws, size_t ws_size,
                              hipStream_t stream) {
    const float* x  = (const float*)d_in[0];
    const float* Wq = (const float*)d_in[1];
    const float* bq = (const float*)d_in[2];
    const float* Wk = (const float*)d_in[3];
    const float* bk = (const float*)d_in[4];
    const float* Wv = (const float*)d_in[5];
    const float* bv = (const float*)d_in[6];
    const float* Wo = (const float*)d_in[7];
    const float* bo = (const float*)d_in[8];
    float* out = (float*)d_out;

    char* ws = (char*)d_ws;
    unsigned short* x_bf  = (unsigned short*)(ws);                      // 16 MB
    unsigned short* wq_bf = (unsigned short*)(ws + 16777216);           //  2 MB
    unsigned short* wk_bf = (unsigned short*)(ws + 18874368);           //  2 MB
    unsigned short* wv_bf = (unsigned short*)(ws + 20971520);           //  2 MB
    unsigned short* q_bf  = (unsigned short*)(ws + 23068672);           // 16 MB (pre-scaled Q)
    unsigned short* k_bf  = (unsigned short*)(ws + 39845888);           // 16 MB
    unsigned short* vt_bf = (unsigned short*)(ws + 56623104);           // 16 MB (V^T, granule-perm)
    float*          accp  = (float*)(ws + 73400320);                    // 16 KB

    conv_all<<<dim3(8192 + 3072), dim3(256), 0, stream>>>(
        x, Wq, Wk, Wv, x_bf, wq_bf, wk_bf, wv_bf, accp);

    qkv_gemm<<<dim3(1536), dim3(256), 0, stream>>>(
        x_bf, wq_bf, wk_bf, wv_bf, bq, bk, bv, q_bf, k_bf, vt_bf);

    attn_mfma<<<dim3(1024), dim3(256), 0, stream>>>(q_bf, k_bf, vt_bf, accp);

    out_proj<<<dim3(16, BATCH), dim3(256), 0, stream>>>(accp, Wo, bo, out);
}

// Round 10
// 285.459 us; speedup vs baseline: 1.4206x; 1.4206x over previous
//
#include <hip/hip_runtime.h>
#include <stdint.h>

#define HIDDEN 1024
#define HEADS 16
#define HEAD_DIM 64
#define BATCH 4
#define SEQ 2048
#define NTOK (BATCH * SEQ)   // 8192

typedef __attribute__((ext_vector_type(8))) short bf16x8;
typedef __attribute__((ext_vector_type(4))) float floatx4;
typedef __attribute__((ext_vector_type(16))) float floatx16;

// log2(e) / sqrt(HEAD_DIM) : folded into Q so p = exp2(s) directly
#define SCALE_Q 0.18033688011112042f

__device__ __forceinline__ unsigned short f2bf(float f) {
    union { float f; unsigned u; } x; x.f = f;
    unsigned r = x.u + 0x7fffu + ((x.u >> 16) & 1u);
    return (unsigned short)(r >> 16);
}

__device__ __forceinline__ float fast_exp2(float x) {
#if __has_builtin(__builtin_amdgcn_exp2f)
    return __builtin_amdgcn_exp2f(x);
#else
    return exp2f(x);
#endif
}

typedef __attribute__((address_space(3))) unsigned int lds_u32;
typedef const __attribute__((address_space(1))) unsigned int gl_u32;

// async global->LDS, 16B per lane; l is the WAVE-UNIFORM base (HW scatters
// lane i's 16B to l + i*16).
__device__ __forceinline__ void async_cp16(const void* g, void* l) {
#if __has_builtin(__builtin_amdgcn_global_load_lds)
    __builtin_amdgcn_global_load_lds((gl_u32*)g, (lds_u32*)l, 16, 0, 0);
#else
    *(uint4*)((char*)l + (threadIdx.x & 63) * 16) = *(const uint4*)g;
#endif
}

// ---- fused fp32->bf16 conversion for x, Wq, Wk, Wv + zero of accp ----------
__global__ __launch_bounds__(256) void conv_all(
    const float* __restrict__ x, const float* __restrict__ Wq,
    const float* __restrict__ Wk, const float* __restrict__ Wv,
    unsigned short* __restrict__ x_bf, unsigned short* __restrict__ wq_bf,
    unsigned short* __restrict__ wk_bf, unsigned short* __restrict__ wv_bf,
    float* __restrict__ accp) {
    const int blk = blockIdx.x, tid = threadIdx.x;
    const float* src;
    unsigned short* dst;
    size_t i;
    if (blk < 8192) {
        src = x; dst = x_bf; i = (size_t)blk * 256 + tid;
        if (blk < 16) accp[blk * 256 + tid] = 0.0f;
    } else {
        int r = blk - 8192;
        int s = r >> 10;
        src = (s == 0) ? Wq : (s == 1) ? Wk : Wv;
        dst = (s == 0) ? wq_bf : (s == 1) ? wk_bf : wv_bf;
        i = (size_t)(r & 1023) * 256 + tid;
    }
    float4 v = *(const float4*)(src + 4 * i);
    unsigned short o[4];
    o[0] = f2bf(v.x); o[1] = f2bf(v.y); o[2] = f2bf(v.z); o[3] = f2bf(v.w);
    *(ushort4*)(dst + 4 * i) = *(ushort4*)o;
}

// ---- QKV GEMM, single N=3072 GEMM of 128x128 tiles (unchanged from R8) -----
__global__ __launch_bounds__(256, 3) void qkv_gemm(
    const unsigned short* __restrict__ X,
    const unsigned short* __restrict__ W0, const unsigned short* __restrict__ W1,
    const unsigned short* __restrict__ W2,
    const float* __restrict__ b0, const float* __restrict__ b1,
    const float* __restrict__ b2,
    unsigned short* __restrict__ O0, unsigned short* __restrict__ O1,
    unsigned short* __restrict__ O2) {
    __shared__ __align__(16) char smem[34816];   // A dbuf 16K | B dbuf 16K; tbuf aliases
    unsigned short* tbuf = (unsigned short*)smem;

    const int id = blockIdx.x;
    const int mb = id & 63, nzb = id >> 6;
    const int z = nzb >> 3, nz = nzb & 7;
    const int m0 = mb * 128;
    const unsigned short* W = (z == 0) ? W0 : (z == 1) ? W1 : W2;
    const float* bias       = (z == 0) ? b0 : (z == 1) ? b1 : b2;

    const int tid = threadIdx.x, lane = tid & 63, wave = tid >> 6;
    const int wm = (wave & 1) * 64, wn = (wave >> 1) * 64;

    const int srow = lane >> 2;
    const int sxc = ((lane & 3) ^ (srow & 3)) * 8;   // shorts
    const unsigned short* ga[2];
    const unsigned short* gb[2];
#pragma unroll
    for (int j = 0; j < 2; ++j) {
        ga[j] = X + (size_t)(m0 + wave * 32 + j * 16 + srow) * HIDDEN + sxc;
        gb[j] = W + (size_t)(nz * 128 + wave * 32 + j * 16 + srow) * HIDDEN + sxc;
    }

    floatx4 acc[4][4];
#pragma unroll
    for (int tm = 0; tm < 4; ++tm)
#pragma unroll
        for (int tn = 0; tn < 4; ++tn)
#pragma unroll
            for (int r = 0; r < 4; ++r) acc[tm][tn][r] = 0.f;

#pragma unroll
    for (int j = 0; j < 2; ++j) {
        async_cp16(ga[j], smem + wave * 2048 + j * 1024);
        async_cp16(gb[j], smem + 16384 + wave * 2048 + j * 1024);
        ga[j] += 32; gb[j] += 32;
    }
    __syncthreads();

    const int fr = (lane & 15) * 64 + (((lane >> 4) ^ (lane & 3)) * 16);
    for (int kt = 0; kt < 32; ++kt) {
        const int cur = kt & 1;
        if (kt < 31) {
#pragma unroll
            for (int j = 0; j < 2; ++j) {
                async_cp16(ga[j], smem + (cur ^ 1) * 8192 + wave * 2048 + j * 1024);
                async_cp16(gb[j], smem + 16384 + (cur ^ 1) * 8192 + wave * 2048 + j * 1024);
                ga[j] += 32; gb[j] += 32;
            }
        }
        const char* Ab = smem + cur * 8192;
        const char* Bb = smem + 16384 + cur * 8192;
        bf16x8 af[4], bfr[4];
#pragma unroll
        for (int t = 0; t < 4; ++t) {
            af[t]  = *(bf16x8*)(Ab + (wm + t * 16) * 64 + fr);
            bfr[t] = *(bf16x8*)(Bb + (wn + t * 16) * 64 + fr);
        }
#pragma unroll
        for (int tm = 0; tm < 4; ++tm)
#pragma unroll
            for (int tn = 0; tn < 4; ++tn)
                acc[tm][tn] = __builtin_amdgcn_mfma_f32_16x16x32_bf16(af[tm], bfr[tn], acc[tm][tn], 0, 0, 0);
        if (kt < 31) __syncthreads();
    }

    // epilogue via LDS transpose; C/D map: col = lane&15, row = (lane>>4)*4+reg
    const int col = lane & 15, rbase = (lane >> 4) * 4;
    __syncthreads();
    if (z == 2) {
        // V: tbuf [d 0..127][tok 0..127], stride 136; granule perm (swap tok
        // bits 2,3) -> attention PV B-frag = one contiguous 16 B chunk.
#pragma unroll
        for (int tm = 0; tm < 4; ++tm)
#pragma unroll
            for (int tn = 0; tn < 4; ++tn) {
                const int dr = wn + tn * 16 + col;
                const float bs = bias[nz * 128 + dr];
                const int mi0 = wm + tm * 16 + rbase;
                const int mip = (mi0 & ~12) | ((mi0 & 4) << 1) | ((mi0 & 8) >> 1);
                unsigned short vals[4];
#pragma unroll
                for (int r = 0; r < 4; ++r) vals[r] = f2bf(acc[tm][tn][r] + bs);
                *(ushort4*)&tbuf[dr * 136 + mip] = *(ushort4*)vals;
            }
        __syncthreads();
        const int dr = tid >> 1, seg = tid & 1;
        const int hh = nz * 2 + (dr >> 6), dd = dr & 63;
        const int bb = m0 >> 11, tb = (m0 & (SEQ - 1)) >> 7;
        unsigned short* dst = O2 + (((size_t)bb * HEADS + hh) * HEAD_DIM + dd) * SEQ
                                 + tb * 128 + seg * 64;
        const unsigned short* srcl = &tbuf[dr * 136 + seg * 64];
#pragma unroll
        for (int i = 0; i < 8; ++i)
            *(uint4*)(dst + i * 8) = *(const uint4*)(srcl + i * 8);
    } else {
        unsigned short* O = (z == 0) ? O0 : O1;
        const float sc = (z == 0) ? SCALE_Q : 1.0f;
#pragma unroll
        for (int tm = 0; tm < 4; ++tm)
#pragma unroll
            for (int tn = 0; tn < 4; ++tn) {
                const int nn = wn + tn * 16 + col;
                const float bs = bias[nz * 128 + nn];
                const int mi0 = wm + tm * 16 + rbase;
#pragma unroll
                for (int r = 0; r < 4; ++r)
                    tbuf[(mi0 + r) * 136 + nn] = f2bf((acc[tm][tn][r] + bs) * sc);
            }
        __syncthreads();
        const int r = tid >> 1, seg = tid & 1;
        unsigned short* dst = O + (size_t)(m0 + r) * HIDDEN + nz * 128 + seg * 64;
        const unsigned short* srcl = &tbuf[r * 136 + seg * 64];
#pragma unroll
        for (int i = 0; i < 8; ++i)
            *(uint4*)(dst + i * 8) = *(const uint4*)(srcl + i * 8);
    }
}

// ---- MFMA flash attention: 256 q/block, 2 q-groups/wave, 64-key dbuf -------
// grid 512. XCD swizzle: all 8 q-chunks of one (b,h) on one XCD.
// 2 q-groups amortize K LDS reads & staging x2 and give two INDEPENDENT
// S-MFMA chains per wave (ILP). 64-key tiles keep LDS at 33 KB -> 3 blocks/CU
// at ~155 unified regs (launch_bounds(256,3)).
// S^T = K·Q^T (C col = query). PV: lane g2 holds keys {0-3,8-11}+4g2 of each
// 16-key step; A-frag = packed pk regs; V B-frag = one b128 (granule perm
// baked into Vt). l accumulated on VALU from the SAME truncated bf16 p values
// (bit-compatible with the old ones-MFMA; verified R9) -> no lacc AGPRs.
__global__ __launch_bounds__(256, 3) void attn_mfma(
    const unsigned short* __restrict__ Q, const unsigned short* __restrict__ K,
    const unsigned short* __restrict__ Vt, float* __restrict__ accp) {
    __shared__ unsigned short Klds[2][4096];  // 64 keys x 64 d, chunk-swizzled
    __shared__ unsigned short Vlds[2][4096];  // 64 d x 64 keys (perm), swizzled
    __shared__ float lbuf[4][2][32];

    const int tid = threadIdx.x, lane = tid & 63, wave = tid >> 6;
    const int lq = lane & 31, g2 = lane >> 5;

    const int f = blockIdx.x;
    const int bh = (f & 7) * 8 + ((f >> 3) & 7);
    const int qc = f >> 6;                    // 0..7 (256-q chunk)
    const int b = bh >> 4, h = bh & 15;

    // Q B-fragments: 2 groups of 32 q per wave, 4 k-slices each
    bf16x8 qfrag[2][4];
#pragma unroll
    for (int g = 0; g < 2; ++g) {
        const size_t qb = ((size_t)(b * SEQ + qc * 256 + wave * 64 + g * 32 + lq)) * HIDDEN
                          + h * HEAD_DIM + g2 * 8;
#pragma unroll
        for (int ds = 0; ds < 4; ++ds) qfrag[g][ds] = *(const bf16x8*)&Q[qb + ds * 16];
    }

    // staging pointers. K: wave w covers key rows [16w,16w+16) (2 instr x 8);
    // V: d-rows [16w,16w+16). XOR chunk swizzle baked into the GLOBAL address
    // so lane-linear LDS writes give the swizzled layout.
    const unsigned short* kg[2];
    const unsigned short* vg[2];
    {
        const int kr = lane >> 3;                       // 0..7
        const int kc = ((lane & 7) ^ kr) * 8;
#pragma unroll
        for (int j = 0; j < 2; ++j)
            kg[j] = K + ((size_t)(b * SEQ + wave * 16 + j * 8 + kr)) * HIDDEN + h * HEAD_DIM + kc;
#pragma unroll
        for (int j = 0; j < 2; ++j) {
            const int dl = wave * 16 + j * 8 + (lane >> 3);
            const int cc = ((lane & 7) ^ (dl & 7)) * 8;
            vg[j] = Vt + ((size_t)bh * HEAD_DIM + dl) * SEQ + cc;
        }
    }

    floatx16 oacc[2][2];
#pragma unroll
    for (int g = 0; g < 2; ++g)
#pragma unroll
        for (int r = 0; r < 16; ++r) { oacc[g][0][r] = 0.f; oacc[g][1][r] = 0.f; }
    float lsum[2] = {0.f, 0.f};

    // prologue: stage tile 0 into buf 0
#pragma unroll
    for (int j = 0; j < 2; ++j) {
        async_cp16(kg[j], (char*)Klds[0] + (wave * 16 + j * 8) * 128);
        async_cp16(vg[j], (char*)Vlds[0] + (wave * 16 + j * 8) * 128);
        kg[j] += 64 * HIDDEN; vg[j] += 64;
    }
    __syncthreads();

    for (int it = 0; it < 32; ++it) {
        const int cur = it & 1;
        if (it < 31) {
#pragma unroll
            for (int j = 0; j < 2; ++j) {
                async_cp16(kg[j], (char*)Klds[cur ^ 1] + (wave * 16 + j * 8) * 128);
                async_cp16(vg[j], (char*)Vlds[cur ^ 1] + (wave * 16 + j * 8) * 128);
                kg[j] += 64 * HIDDEN; vg[j] += 64;
            }
        }
#pragma unroll
        for (int s32 = 0; s32 < 2; ++s32) {
            const int rr = s32 * 32 + lq;
            bf16x8 kf[4];
#pragma unroll
            for (int ds = 0; ds < 4; ++ds)
                kf[ds] = *(bf16x8*)((char*)Klds[cur] + rr * 128 + (((g2 + 2 * ds) ^ (lq & 7)) * 16));
            // V B-frags for both 16-key steps of this 32-key half (shared by
            // both q-groups)
            bf16x8 vf[2][2];
#pragma unroll
            for (int ks2 = 0; ks2 < 2; ++ks2)
#pragma unroll
                for (int nf = 0; nf < 2; ++nf) {
                    const int d = nf * 32 + lq;
                    const int c = (2 * (s32 * 2 + ks2) + g2) ^ (d & 7);
                    vf[ks2][nf] = *(bf16x8*)((char*)Vlds[cur] + d * 128 + c * 16);
                }
#pragma unroll
            for (int g = 0; g < 2; ++g) {
                floatx16 sacc;
#pragma unroll
                for (int r = 0; r < 16; ++r) sacc[r] = 0.f;
#pragma unroll
                for (int ds = 0; ds < 4; ++ds)
                    sacc = __builtin_amdgcn_mfma_f32_32x32x16_bf16(kf[ds], qfrag[g][ds], sacc, 0, 0, 0);

                unsigned pk[8];
#pragma unroll
                for (int j = 0; j < 8; ++j) {
                    union { float f; unsigned u; } plo, phi;
                    plo.f = fast_exp2(sacc[2 * j]);
                    phi.f = fast_exp2(sacc[2 * j + 1]);
                    pk[j] = __builtin_amdgcn_perm(phi.u, plo.u, 0x07060302u);
                    union { unsigned u; float f; } tlo, thi;
                    tlo.u = pk[j] << 16;          // truncated p values: l is
                    thi.u = pk[j] & 0xFFFF0000u;  // bit-compatible with PV
                    lsum[g] += tlo.f + thi.f;
                }
#pragma unroll
                for (int ks2 = 0; ks2 < 2; ++ks2) {
                    union { uint4 u; bf16x8 v; } af;
                    af.u.x = pk[4 * ks2];
                    af.u.y = pk[4 * ks2 + 1];
                    af.u.z = pk[4 * ks2 + 2];
                    af.u.w = pk[4 * ks2 + 3];
#pragma unroll
                    for (int nf = 0; nf < 2; ++nf)
                        oacc[g][nf] = __builtin_amdgcn_mfma_f32_32x32x16_bf16(af.v, vf[ks2][nf], oacc[g][nf], 0, 0, 0);
                }
            }
        }
        if (it < 31) __syncthreads();
    }

    // ---- epilogue ----------------------------------------------------------
    // full l per query: add the other g2-half, stash per-wave, reload in
    // C-row layout (row r of group g = query (r&3)+8*(r>>2)+4*g2).
#pragma unroll
    for (int g = 0; g < 2; ++g) {
        float ls = lsum[g] + __shfl_xor(lsum[g], 32, 64);
        if (lane < 32) lbuf[wave][g][lq] = ls;
    }
    __builtin_amdgcn_s_waitcnt(0);   // same-wave LDS visibility
    float inv[2][16];
#pragma unroll
    for (int g = 0; g < 2; ++g)
#pragma unroll
        for (int c = 0; c < 4; ++c) {
            float4 l4 = *(float4*)&lbuf[wave][g][c * 8 + g2 * 4];
            inv[g][4 * c + 0] = 1.0f / l4.x;
            inv[g][4 * c + 1] = 1.0f / l4.y;
            inv[g][4 * c + 2] = 1.0f / l4.z;
            inv[g][4 * c + 3] = 1.0f / l4.w;
        }
#pragma unroll
    for (int nf = 0; nf < 2; ++nf) {
        float v = 0.f;
#pragma unroll
        for (int g = 0; g < 2; ++g)
#pragma unroll
            for (int r = 0; r < 16; ++r) v += oacc[g][nf][r] * inv[g][r];
        v += __shfl_xor(v, 32, 64);
        if (lane < 32)
            atomicAdd(&accp[b * HIDDEN + h * HEAD_DIM + nf * 32 + lq], v);
    }
}

// ---- final projection: out = (acc/T) @ Wo^T + bo, split-k x4 ---------------
__global__ __launch_bounds__(256) void out_proj(const float* __restrict__ acc,
                                                const float* __restrict__ Wo,
                                                const float* __restrict__ bo,
                                                float* __restrict__ out) {
    __shared__ float red[256];
    const int n = blockIdx.x * 64 + (threadIdx.x & 63);
    const int ks = threadIdx.x >> 6;       // 0..3
    const int b = blockIdx.y;
    const float* wr = Wo + (size_t)n * HIDDEN + ks * 256;
    const float* ar = acc + b * HIDDEN + ks * 256;
    float s = 0.f;
#pragma unroll 8
    for (int k = 0; k < 256; k += 4) {
        float4 w = *(const float4*)(wr + k);
        float4 a = *(const float4*)(ar + k);
        s += w.x * a.x + w.y * a.y + w.z * a.z + w.w * a.w;
    }
    red[threadIdx.x] = s;
    __syncthreads();
    if (threadIdx.x < 64) {
        float t = red[threadIdx.x] + red[threadIdx.x + 64]
                + red[threadIdx.x + 128] + red[threadIdx.x + 192];
        out[b * HIDDEN + n] = t * (1.0f / (float)SEQ) + bo[n];
    }
}

extern "C" void kernel_launch(void* const* d_in, const int* in_sizes, int n_in,
                              void* d_out, int out_size, void* d_ws, size_t ws_size,
                              hipStream_t stream) {
    const float* x  = (const float*)d_in[0];
    const float* Wq = (const float*)d_in[1];
    const float* bq = (const float*)d_in[2];
    const float* Wk = (const float*)d_in[3];
    const float* bk = (const float*)d_in[4];
    const float* Wv = (const float*)d_in[5];
    const float* bv = (const float*)d_in[6];
    const float* Wo = (const float*)d_in[7];
    const float* bo = (const float*)d_in[8];
    float* out = (float*)d_out;

    char* ws = (char*)d_ws;
    unsigned short* x_bf  = (unsigned short*)(ws);                      // 16 MB
    unsigned short* wq_bf = (unsigned short*)(ws + 16777216);           //  2 MB
    unsigned short* wk_bf = (unsigned short*)(ws + 18874368);           //  2 MB
    unsigned short* wv_bf = (unsigned short*)(ws + 20971520);           //  2 MB
    unsigned short* q_bf  = (unsigned short*)(ws + 23068672);           // 16 MB (pre-scaled Q)
    unsigned short* k_bf  = (unsigned short*)(ws + 39845888);           // 16 MB
    unsigned short* vt_bf = (unsigned short*)(ws + 56623104);           // 16 MB (V^T, granule-perm)
    float*          accp  = (float*)(ws + 73400320);                    // 16 KB

    conv_all<<<dim3(8192 + 3072), dim3(256), 0, stream>>>(
        x, Wq, Wk, Wv, x_bf, wq_bf, wk_bf, wv_bf, accp);

    qkv_gemm<<<dim3(1536), dim3(256), 0, stream>>>(
        x_bf, wq_bf, wk_bf, wv_bf, bq, bk, bv, q_bf, k_bf, vt_bf);

    attn_mfma<<<dim3(512), dim3(256), 0, stream>>>(q_bf, k_bf, vt_bf, accp);

    out_proj<<<dim3(16, BATCH), dim3(256), 0, stream>>>(accp, Wo, bo, out);
}